// Round 11
// baseline (401.916 us; speedup 1.0000x reference)
//
#include <hip/hip_runtime.h>

#define SS 512
#define BB 512
#define TT 64
#define NTHREADS 256
#define NBLK (BB / 2)
#define FSTRIDE ((size_t)BB * TT)
#define HISTBYTES ((SS - 1) * TT)                 // 32704 per sequence
#define DYNLDS (1024 + 2 * HISTBYTES)             // vbufA+vbufB + two hists = 66432

// DPP quad_perm helpers (validated R2-R10): xor1=0xB1, xor2=0x4E
template <int CTRL>
__device__ __forceinline__ float dppf(float x) {
    return __int_as_float(__builtin_amdgcn_mov_dpp(__float_as_int(x), CTRL, 0xF, 0xF, true));
}
template <int CTRL>
__device__ __forceinline__ int dppi(int x) {
    return __builtin_amdgcn_mov_dpp(x, CTRL, 0xF, 0xF, true);
}

// Drain LDS ops only; emission prefetch loads stay in flight across barrier.
__device__ __forceinline__ void barrier_lgkm() {
    asm volatile("s_waitcnt lgkmcnt(0)\n\ts_barrier" ::: "memory");
}

// One block per PAIR of sequences (bA = x, bB = x + 256). 4 waves;
// tid -> (j = tid>>2, li = tid&3); lane covers sources [li*16, li*16+16).
// Per step: bodyA ; bodyB ; ONE barrier -- A's LDS turnaround hides under
// B's compute in the same instruction stream, halving per-seq step cost.
__global__ __launch_bounds__(NTHREADS) void viterbi_pair(
    const float* __restrict__ feats,   // (S,B,T)
    const float* __restrict__ mask,    // (B,S)
    const float* __restrict__ startt,  // (T,)
    const float* __restrict__ endt,    // (T,)
    const float* __restrict__ trans,   // (T,T)
    int* __restrict__ out)             // (B,S)
{
    extern __shared__ __align__(16) char smem[];
    float (*vbufA)[TT] = (float (*)[TT])(smem);          // [2][64] f32
    float (*vbufB)[TT] = (float (*)[TT])(smem + 512);    // [2][64] f32
    unsigned char* histA = (unsigned char*)(smem + 1024);
    unsigned char* histB = histA + HISTBYTES;

    __shared__ float redA[4], redB[4];
    __shared__ int lenShA, lenShB;

    const int bA  = blockIdx.x;
    const int bB  = blockIdx.x + NBLK;
    const int tid = threadIdx.x;
    const int j   = tid >> 2;
    const int li  = tid & 3;
    const int base_i = li * 16;
    const int wid = tid >> 6;
    const int lane = tid & 63;

    // transitions column slice (same for both sequences)
    float tcr[16];
#pragma unroll
    for (int k = 0; k < 16; ++k) tcr[k] = trans[(base_i + k) * TT + j];

    // init v0 for both sequences
    if (tid < TT) {
        vbufA[0][tid] = startt[tid] + feats[(size_t)bA * TT + tid];
        vbufB[0][tid] = startt[tid] + feats[(size_t)bB * TT + tid];
    }

    // lengths (exact 0/1 fp sums)
    float msA = mask[bA * SS + tid] + mask[bA * SS + 256 + tid];
    float msB = mask[bB * SS + tid] + mask[bB * SS + 256 + tid];
#pragma unroll
    for (int off = 1; off < 64; off <<= 1) {
        msA += __shfl_xor(msA, off);
        msB += __shfl_xor(msB, off);
    }
    if (lane == 0) { redA[wid] = msA; redB[wid] = msB; }
    __syncthreads();
    if (tid == 0) {
        lenShA = (int)(redA[0] + redA[1] + redA[2] + redA[3] + 0.5f);
        lenShB = (int)(redB[0] + redB[1] + redB[2] + redB[3] + 0.5f);
    }
    __syncthreads();

    const int lenA = lenShA;
    const int lenB = lenShB;
    const int smax = (lenA > lenB) ? lenA : lenB;
    int pA = 0, pB = 0;

    const float* fbA = feats + (size_t)bA * TT + j;
    const float* fbB = feats + (size_t)bB * TT + j;

    // R3's verified step body, parameterized (no barrier inside)
    auto body = [&](float (*vbuf)[TT], unsigned char* hist, int p, float e, int s) {
        float v[16];
#pragma unroll
        for (int q = 0; q < 4; ++q) {
            float4 t4 = *(const float4*)&vbuf[p][base_i + q * 4];
            v[q * 4 + 0] = t4.x; v[q * 4 + 1] = t4.y;
            v[q * 4 + 2] = t4.z; v[q * 4 + 3] = t4.w;
        }
        float sc[16];
#pragma unroll
        for (int k = 0; k < 16; ++k) sc[k] = (v[k] + tcr[k]) + e;

        float c0 = sc[0];  int x0 = 0;
        float c1 = sc[4];  int x1 = 4;
        float c2 = sc[8];  int x2 = 8;
        float c3 = sc[12]; int x3 = 12;
#pragma unroll
        for (int k = 1; k < 4; ++k) {
            if (sc[k]      > c0) { c0 = sc[k];      x0 = k; }
            if (sc[4 + k]  > c1) { c1 = sc[4 + k];  x1 = 4 + k; }
            if (sc[8 + k]  > c2) { c2 = sc[8 + k];  x2 = 8 + k; }
            if (sc[12 + k] > c3) { c3 = sc[12 + k]; x3 = 12 + k; }
        }
        if (c1 > c0) { c0 = c1; x0 = x1; }
        if (c3 > c2) { c2 = c3; x2 = x3; }
        if (c2 > c0) { c0 = c2; x0 = x2; }
        float best = c0;
        int   bi   = base_i + x0;

        {
            float ov = dppf<0xB1>(best);
            int   oi = dppi<0xB1>(bi);
            if (ov > best || (ov == best && oi < bi)) { best = ov; bi = oi; }
            ov = dppf<0x4E>(best);
            oi = dppi<0x4E>(bi);
            if (ov > best || (ov == best && oi < bi)) { best = ov; bi = oi; }
        }

        if (li == 0) {
            vbuf[p ^ 1][j] = best;
            hist[(s - 1) * TT + j] = (unsigned char)bi;
        }
    };

    // emissions: 8-deep chunked prefetch for both sequences
    float ecA[8], enA[8], ecB[8], enB[8];
#pragma unroll
    for (int u = 0; u < 8; ++u) {
        int sn = 1 + u; if (sn > SS - 1) sn = SS - 1;
        ecA[u] = fbA[(size_t)sn * FSTRIDE];
        ecB[u] = fbB[(size_t)sn * FSTRIDE];
    }

    int s = 1;
    while (s + 8 <= smax) {
#pragma unroll
        for (int u = 0; u < 8; ++u) {
            int sn = s + 8 + u; if (sn > SS - 1) sn = SS - 1;
            enA[u] = fbA[(size_t)sn * FSTRIDE];
            enB[u] = fbB[(size_t)sn * FSTRIDE];
        }
#pragma unroll
        for (int u = 0; u < 8; ++u) {
            const bool rA = (s + u < lenA), rB = (s + u < lenB);
            if (rA) body(vbufA, histA, pA, ecA[u], s + u);
            if (rB) body(vbufB, histB, pB, ecB[u], s + u);
            barrier_lgkm();
            if (rA) pA ^= 1;
            if (rB) pB ^= 1;
        }
#pragma unroll
        for (int u = 0; u < 8; ++u) { ecA[u] = enA[u]; ecB[u] = enB[u]; }
        s += 8;
    }
#pragma unroll
    for (int u = 0; u < 7; ++u) {
        if (s + u < smax) {
            const bool rA = (s + u < lenA), rB = (s + u < lenB);
            if (rA) body(vbufA, histA, pA, ecA[u], s + u);
            if (rB) body(vbufB, histB, pB, ecB[u], s + u);
            barrier_lgkm();
            if (rA) pA ^= 1;
            if (rB) pB ^= 1;
        }
    }

    // epilogue: wave0 finalizes A, wave1 finalizes B, waves 2/3 zero-fill
    if (tid < TT) {
        float fv = vbufA[pA][lane] + endt[lane];
        int bix = lane;
#pragma unroll
        for (int off = 1; off < 64; off <<= 1) {
            float ov = __shfl_xor(fv, off);
            int   oi = __shfl_xor(bix, off);
            if (ov > fv || (ov == fv && oi < bix)) { fv = ov; bix = oi; }
        }
        if (lane == 0) {
            int* ob = out + (size_t)bA * SS;
            int cur = bix;
            ob[SS - 1] = cur;
            ob[lenA - 1] = cur;
            for (int s2 = lenA - 2; s2 >= 0; --s2) {
                cur = histA[s2 * TT + cur];
                ob[s2] = cur;
            }
        }
    } else if (tid < 2 * TT) {
        float fv = vbufB[pB][lane] + endt[lane];
        int bix = lane;
#pragma unroll
        for (int off = 1; off < 64; off <<= 1) {
            float ov = __shfl_xor(fv, off);
            int   oi = __shfl_xor(bix, off);
            if (ov > fv || (ov == fv && oi < bix)) { fv = ov; bix = oi; }
        }
        if (lane == 0) {
            int* ob = out + (size_t)bB * SS;
            int cur = bix;
            ob[SS - 1] = cur;
            ob[lenB - 1] = cur;
            for (int s2 = lenB - 2; s2 >= 0; --s2) {
                cur = histB[s2 * TT + cur];
                ob[s2] = cur;
            }
        }
    } else if (tid < 3 * TT) {
        for (int s2 = lenA + lane; s2 < SS - 1; s2 += TT)
            out[(size_t)bA * SS + s2] = 0;
    } else {
        for (int s2 = lenB + lane; s2 < SS - 1; s2 += TT)
            out[(size_t)bB * SS + s2] = 0;
    }
}

extern "C" void kernel_launch(void* const* d_in, const int* in_sizes, int n_in,
                              void* d_out, int out_size, void* d_ws, size_t ws_size,
                              hipStream_t stream) {
    const float* feats  = (const float*)d_in[0];
    const float* mask   = (const float*)d_in[1];
    const float* startt = (const float*)d_in[2];
    const float* endt   = (const float*)d_in[3];
    const float* trans  = (const float*)d_in[4];
    int* out = (int*)d_out;

    // allow >64KB dynamic LDS (66,432 B used); idempotent, not a stream op
    hipFuncSetAttribute((const void*)viterbi_pair,
                        hipFuncAttributeMaxDynamicSharedMemorySize, DYNLDS);

    viterbi_pair<<<dim3(NBLK), dim3(NTHREADS), DYNLDS, stream>>>(
        feats, mask, startt, endt, trans, out);
}